// Round 2
// baseline (3539.098 us; speedup 1.0000x reference)
//
#include <hip/hip_runtime.h>

// ---------- constants ----------
#define B_    16
#define NCTX  8
#define BIN_  256
#define LQ_   256
#define L_    520          // NCTX + BIN + LQ
#define LSEQ  1024
#define D_    1024
#define H_    16
#define DH    64
#define DFF_  4096
#define DEPTH 6
#define MROWS (B_ * L_)    // 8320 real rows
#define MP    8448         // padded to 33*256 for 256-tile GEMM

using bf16x8 = __attribute__((ext_vector_type(8))) __bf16;
using bf16x4 = __attribute__((ext_vector_type(4))) __bf16;
using f32x4  = __attribute__((ext_vector_type(4))) float;

#define DEV __device__ __forceinline__

// element offset into a [rows][64] bf16 tile, XOR-swizzled 16B chunks
DEV int swz(int r, int c) { return (r << 6) + (((c ^ r) & 7) << 3); }

#define GLDS16(g, l)                                                         \
  __builtin_amdgcn_global_load_lds(                                          \
      (__attribute__((address_space(1))) void*)(g),                          \
      (__attribute__((address_space(3))) void*)(l), 16, 0, 0)

// ---------- prologue kernels ----------

// Te[b][pos]: time key per decoder position. Also per-64-tile min (K side)
// and max over REAL rows only (Q side) for attention tile skipping.
__global__ void te_k(const int* __restrict__ qtime, int* __restrict__ Te,
                     int* __restrict__ TeMinK, int* __restrict__ TeMaxQ) {
  int b = blockIdx.x, pos = threadIdx.x;
  __shared__ int smin[9], smax[9];
  if (pos < 9) { smin[pos] = 0x7fffffff; smax[pos] = (int)0x80000000; }
  __syncthreads();
  int v;
  if (pos < NCTX) v = (int)0x80000000;
  else if (pos < NCTX + BIN_) v = pos - NCTX;
  else if (pos < L_) v = qtime[b * LQ_ + (pos - NCTX - BIN_)];
  else v = 0x7fffffff;
  Te[b * 576 + pos] = v;
  int vq = (pos < L_) ? v : (int)0x80000000;
  atomicMin(&smin[pos >> 6], v);
  atomicMax(&smax[pos >> 6], vq);
  __syncthreads();
  if (pos < 9) { TeMinK[b * 9 + pos] = smin[pos]; TeMaxQ[b * 9 + pos] = smax[pos]; }
}

// mean-pool latents per time bin, add time embedding, write h rows 8..263
__global__ void pool_k(const float* __restrict__ latents,
                       const int* __restrict__ tIdx,
                       const float* __restrict__ temb, float* __restrict__ h) {
  int s = blockIdx.x, b = blockIdx.y, tid = threadIdx.x;
  __shared__ int sIdx[LSEQ];
#pragma unroll
  for (int j = 0; j < 4; ++j) sIdx[tid + 256 * j] = tIdx[b * LSEQ + tid + 256 * j];
  __syncthreads();
  float a0 = 0.f, a1 = 0.f, a2 = 0.f, a3 = 0.f;
  int cnt = 0;
  const float4* L = (const float4*)(latents + (size_t)b * LSEQ * D_);
  for (int l = 0; l < LSEQ; ++l) {
    if (sIdx[l] == s) {
      float4 v = L[(size_t)l * 256 + tid];
      a0 += v.x; a1 += v.y; a2 += v.z; a3 += v.w; ++cnt;
    }
  }
  float inv = 1.f / (float)(cnt > 0 ? cnt : 1);
  float4 te = ((const float4*)(temb + (size_t)s * D_))[tid];
  float4 o;
  o.x = a0 * inv + te.x; o.y = a1 * inv + te.y;
  o.z = a2 * inv + te.z; o.w = a3 * inv + te.w;
  ((float4*)(h + ((size_t)b * L_ + NCTX + s) * D_))[tid] = o;
}

// ctx rows (0..7) + query rows (264..519)
__global__ void qrows_k(const float* __restrict__ ctx,
                        const float* __restrict__ qemb,
                        const float* __restrict__ temb,
                        const int* __restrict__ qidx,
                        const int* __restrict__ qtime, float* __restrict__ h) {
  int r = blockIdx.x, b = blockIdx.y, tid = threadIdx.x;
  if (r < NCTX) {
    float4 v = ((const float4*)(ctx + ((size_t)b * NCTX + r) * D_))[tid];
    ((float4*)(h + ((size_t)b * L_ + r) * D_))[tid] = v;
  } else {
    int q = r - NCTX;
    int qi = qidx[b * LQ_ + q];
    int qt = qtime[b * LQ_ + q];
    float4 e = ((const float4*)(qemb + (size_t)qi * D_))[tid];
    float4 t = ((const float4*)(temb + (size_t)qt * D_))[tid];
    float4 o; o.x = e.x + t.x; o.y = e.y + t.y; o.z = e.z + t.z; o.w = e.w + t.w;
    ((float4*)(h + ((size_t)b * L_ + NCTX + BIN_ + q) * D_))[tid] = o;
  }
}

// fp32 -> bf16 (grid-stride over float4s)
__global__ void cvt_k(const float* __restrict__ src, __bf16* __restrict__ dst, int n4) {
  for (int i = blockIdx.x * blockDim.x + threadIdx.x; i < n4; i += gridDim.x * blockDim.x) {
    float4 v = ((const float4*)src)[i];
    bf16x4 o;
    o[0] = (__bf16)v.x; o[1] = (__bf16)v.y; o[2] = (__bf16)v.z; o[3] = (__bf16)v.w;
    ((bf16x4*)dst)[i] = o;
  }
}

// LayerNorm over D=1024, fp32 in -> bf16 out
__global__ __launch_bounds__(256) void ln_k(const float* __restrict__ h,
                                            const float* __restrict__ s,
                                            const float* __restrict__ bb,
                                            __bf16* __restrict__ y) {
  int row = blockIdx.x, tid = threadIdx.x;
  int lane = tid & 63, wave = tid >> 6;
  float4 v = ((const float4*)(h + (size_t)row * D_))[tid];
  float sum = v.x + v.y + v.z + v.w;
  float sq  = v.x * v.x + v.y * v.y + v.z * v.z + v.w * v.w;
#pragma unroll
  for (int m = 32; m; m >>= 1) { sum += __shfl_xor(sum, m); sq += __shfl_xor(sq, m); }
  __shared__ float red[8];
  if (lane == 0) { red[wave] = sum; red[4 + wave] = sq; }
  __syncthreads();
  sum = red[0] + red[1] + red[2] + red[3];
  sq  = red[4] + red[5] + red[6] + red[7];
  float mean = sum * (1.f / D_);
  float var  = sq * (1.f / D_) - mean * mean;
  float rstd = rsqrtf(var + 1e-5f);
  float4 sv = ((const float4*)s)[tid];
  float4 bv = ((const float4*)bb)[tid];
  bf16x4 o;
  o[0] = (__bf16)((v.x - mean) * rstd * sv.x + bv.x);
  o[1] = (__bf16)((v.y - mean) * rstd * sv.y + bv.y);
  o[2] = (__bf16)((v.z - mean) * rstd * sv.z + bv.z);
  o[3] = (__bf16)((v.w - mean) * rstd * sv.w + bv.w);
  *(bf16x4*)(y + (size_t)row * D_ + tid * 4) = o;
}

// ---------- 256x256 8-phase GEMM: C[M,N] = A[M,K] * Bw[N,K]^T + bias ----------
// 8 waves (2M x 4N), per-wave C = 128x64. LDS: A/B as [2dbuf][2half][128][64],
// where A-half h = rows {h*64..h*64+63} U {128+h*64..}, i.e. the mq read-set;
// B-half = the nq read-set. Each phase stages ONE half-tile (2 gload_lds/wave)
// into a slot freed exactly one phase earlier; vmcnt(4) only at phases 4/8.
// EPI 0: store bf16; 1: outF += val (fp32 residual); 2: gelu -> bf16
#define STG_A(dbuf, half, ktile)                                              \
  do {                                                                        \
    const __bf16* _s = Aba + (size_t)(ktile) * 64;                            \
    _Pragma("unroll") for (int _k = 0; _k < 2; ++_k) {                        \
      int _rq = wave * 16 + _k * 8 + (lane >> 3);                             \
      int _r = (_rq & 63) + ((half) << 6) + ((_rq >> 6) << 7);                \
      GLDS16(_s + (size_t)_r * K + (((lane & 7) ^ (_rq & 7)) << 3),           \
             sA[dbuf][half] + (wave * 16 + _k * 8) * 64);                     \
    }                                                                         \
  } while (0)

#define STG_B(dbuf, half, ktile)                                              \
  do {                                                                        \
    const __bf16* _s = Bba + (size_t)(ktile) * 64;                            \
    _Pragma("unroll") for (int _k = 0; _k < 2; ++_k) {                        \
      int _rq = wave * 16 + _k * 8 + (lane >> 3);                             \
      int _r = (_rq & 31) + ((half) << 5) + ((_rq >> 5) << 6);                \
      GLDS16(_s + (size_t)_r * K + (((lane & 7) ^ (_rq & 7)) << 3),           \
             sB[dbuf][half] + (wave * 16 + _k * 8) * 64);                     \
    }                                                                         \
  } while (0)

#define VMW4 asm volatile("s_waitcnt vmcnt(4)" ::: "memory")

#define PHASE(dbuf, mq, nq, STGSTMT, VMWAIT)                                  \
  {                                                                           \
    if ((nq) == 0) {                                                          \
      _Pragma("unroll") for (int _i = 0; _i < 4; ++_i)                        \
        _Pragma("unroll") for (int _kk = 0; _kk < 2; ++_kk)                   \
          areg[_i][_kk] = *(const bf16x8*)(sA[dbuf][mq] +                     \
              (wr * 64 + _i * 16 + lr) * 64 + (((_kk * 4 + lq) ^ lr7) << 3)); \
    }                                                                         \
    bf16x8 breg[2][2];                                                        \
    _Pragma("unroll") for (int _j = 0; _j < 2; ++_j)                          \
      _Pragma("unroll") for (int _kk = 0; _kk < 2; ++_kk)                     \
        breg[_j][_kk] = *(const bf16x8*)(sB[dbuf][nq] +                       \
            (wc * 32 + _j * 16 + lr) * 64 + (((_kk * 4 + lq) ^ lr7) << 3));   \
    STGSTMT;                                                                  \
    __builtin_amdgcn_s_barrier();                                             \
    __builtin_amdgcn_s_setprio(1);                                            \
    _Pragma("unroll") for (int _i = 0; _i < 4; ++_i)                          \
      _Pragma("unroll") for (int _j = 0; _j < 2; ++_j)                        \
        _Pragma("unroll") for (int _kk = 0; _kk < 2; ++_kk)                   \
          acc[(mq) * 4 + _i][(nq) * 2 + _j] =                                 \
              __builtin_amdgcn_mfma_f32_16x16x32_bf16(                        \
                  areg[_i][_kk], breg[_j][_kk],                               \
                  acc[(mq) * 4 + _i][(nq) * 2 + _j], 0, 0, 0);                \
    __builtin_amdgcn_s_setprio(0);                                            \
    VMWAIT;                                                                   \
    __builtin_amdgcn_s_barrier();                                             \
  }

template <int EPI>
__global__ __launch_bounds__(512, 2) void gemm256_k(const __bf16* __restrict__ A,
                                                    const __bf16* __restrict__ Bw,
                                                    const float* __restrict__ bias,
                                                    __bf16* __restrict__ outB,
                                                    float* __restrict__ outF,
                                                    int N, int K, int gx) {
  __shared__ __bf16 sA[2][2][128 * 64];
  __shared__ __bf16 sB[2][2][128 * 64];
  const int tid = threadIdx.x;
  const int lane = tid & 63, wave = tid >> 6;
  const int lr = lane & 15, lq = lane >> 4;
  const int lr7 = lr & 7;
  const int wr = wave >> 2, wc = wave & 3;

  // XCD-bijective remap (m204): same-XCD blocks get contiguous tile ids
  const int nwg = gridDim.x;
  int hid = blockIdx.x;
  int q8 = nwg >> 3, r8 = nwg & 7;
  int xcd = hid & 7, within = hid >> 3;
  int lid = (xcd < r8 ? xcd * (q8 + 1) : r8 * (q8 + 1) + (xcd - r8) * q8) + within;
  int bx = lid % gx, by = lid / gx;
  const size_t bm = (size_t)by * 256, bn = (size_t)bx * 256;

  const __bf16* Aba = A + bm * (size_t)K;
  const __bf16* Bba = Bw + bn * (size_t)K;

  f32x4 acc[8][4] = {};
  bf16x8 areg[4][2];

  const int nk = K >> 6;    // 16 or 64, always even
  const int nit = nk >> 1;

  // prologue: tile0 (A0,B0,A1,B1) + tile1 (A0,B0); then t0 landed, 2 halves in flight
  STG_A(0, 0, 0); STG_B(0, 0, 0); STG_A(0, 1, 0); STG_B(0, 1, 0);
  STG_A(1, 0, 1); STG_B(1, 0, 1);
  VMW4;
  __builtin_amdgcn_s_barrier();

  for (int it = 0; it < nit; ++it) {
    const int to = 2 * it + 1, t2 = 2 * it + 2, t3 = 2 * it + 3;
    const bool more = (it + 1 < nit);
    // group-even: compute tile 2it from buf0
    PHASE(0, 0, 0, { STG_A(1, 1, to); }, ((void)0));
    PHASE(0, 0, 1, { STG_B(1, 1, to); }, ((void)0));
    PHASE(0, 1, 0, { if (more) STG_A(0, 0, t2); }, ((void)0));
    PHASE(0, 1, 1, { if (more) STG_B(0, 0, t2); }, VMW4);
    // group-odd: compute tile 2it+1 from buf1
    PHASE(1, 0, 0, { if (more) STG_A(0, 1, t2); }, ((void)0));
    PHASE(1, 0, 1, { if (more) STG_B(0, 1, t2); }, ((void)0));
    PHASE(1, 1, 0, { if (more) STG_A(1, 0, t3); }, ((void)0));
    PHASE(1, 1, 1, { if (more) STG_B(1, 0, t3); }, VMW4);
  }

  // epilogue
#pragma unroll
  for (int nj = 0; nj < 4; ++nj) {
    int cg = (int)bn + wc * 64 + (nj >> 1) * 32 + (nj & 1) * 16 + lr;
    float bl = bias[cg];
#pragma unroll
    for (int mi = 0; mi < 8; ++mi) {
      f32x4 v = acc[mi][nj];
      int rbase = (int)bm + wr * 128 + (mi >> 2) * 64 + (mi & 3) * 16 + lq * 4;
#pragma unroll
      for (int ii = 0; ii < 4; ++ii) {
        int rg = rbase + ii;
        float val = v[ii] + bl;
        if (EPI == 0) {
          outB[(size_t)rg * N + cg] = (__bf16)val;
        } else if (EPI == 1) {
          outF[(size_t)rg * N + cg] += val;
        } else {
          float g = 0.5f * val * (1.0f + erff(val * 0.70710678118f));
          outB[(size_t)rg * N + cg] = (__bf16)g;
        }
      }
    }
  }
}

// ---------- attention ----------
// grid (qt=9, h=16, b=16), 256 threads (4 waves); each wave owns 16 q rows.
// Fully-masked (qt,kt) tile pairs are skipped (time keys sorted).
__global__ __launch_bounds__(256) void attn_k(const __bf16* __restrict__ qkv,
                                              const int* __restrict__ Te,
                                              const int* __restrict__ TeMinK,
                                              const int* __restrict__ TeMaxQ,
                                              __bf16* __restrict__ o) {
  const int qt = blockIdx.x, hh = blockIdx.y, b = blockIdx.z;
  const int tid = threadIdx.x;
  const int lane = tid & 63, wave = tid >> 6;
  const int lr = lane & 15, lq = lane >> 4;
  __shared__ __bf16 sQ[64 * 64], sK[64 * 64], sV[64 * 64];
  __shared__ __bf16 sP[4][16 * 64];
  __shared__ int sTq[64], sTk[64];

  if (tid < 64) sTq[tid] = Te[b * 576 + qt * 64 + tid];
  const int maxQ = TeMaxQ[b * 9 + qt];

  const __bf16* base = qkv + (size_t)b * L_ * (3 * D_) + hh * DH;
  // stage Q (swizzled write, zero-fill invalid rows)
#pragma unroll
  for (int j = 0; j < 2; ++j) {
    int q = tid + j * 256;
    int r = q >> 3, c = q & 7;
    int rg = qt * 64 + r;
    bf16x8 v = {};
    if (rg < L_) v = *(const bf16x8*)(base + (size_t)rg * (3 * D_) + c * 8);
    *(bf16x8*)(sQ + swz(r, c)) = v;
  }

  float m_run[4], l_run[4];
#pragma unroll
  for (int i = 0; i < 4; ++i) { m_run[i] = -1e30f; l_run[i] = 0.f; }
  f32x4 oacc[4] = {};
  const float scale = 0.125f;

  for (int kt = 0; kt < 9; ++kt) {
    if (TeMinK[b * 9 + kt] > maxQ) continue;  // tile fully masked (uniform)
    __syncthreads();  // previous tile fully consumed
    if (tid < 64) sTk[tid] = Te[b * 576 + kt * 64 + tid];
#pragma unroll
    for (int j = 0; j < 2; ++j) {
      int q = tid + j * 256;
      int r = q >> 3, c = q & 7;
      int rg = kt * 64 + r;
      bf16x8 kv = {}, vv = {};
      if (rg < L_) {
        kv = *(const bf16x8*)(base + D_ + (size_t)rg * (3 * D_) + c * 8);
        vv = *(const bf16x8*)(base + 2 * D_ + (size_t)rg * (3 * D_) + c * 8);
      }
      *(bf16x8*)(sK + swz(r, c)) = kv;       // swizzled
      *(bf16x8*)(sV + r * 64 + c * 8) = vv;  // linear
    }
    __syncthreads();

    // S = Q K^T (wave strip: rows wave*16..+16, cols 0..64)
    f32x4 sacc[4] = {};
#pragma unroll
    for (int kk = 0; kk < 2; ++kk) {
      bf16x8 aq = *(const bf16x8*)(sQ + swz(wave * 16 + lr, kk * 4 + lq));
#pragma unroll
      for (int cn = 0; cn < 4; ++cn) {
        bf16x8 bk = *(const bf16x8*)(sK + swz(cn * 16 + lr, kk * 4 + lq));
        sacc[cn] = __builtin_amdgcn_mfma_f32_16x16x32_bf16(aq, bk, sacc[cn], 0, 0, 0);
      }
    }
    // mask + online softmax (rows: lq*4+i, cols: cn*16+lr)
    float sval[4][4], mt[4];
#pragma unroll
    for (int i = 0; i < 4; ++i) mt[i] = -1e30f;
#pragma unroll
    for (int cn = 0; cn < 4; ++cn) {
      int tk = sTk[cn * 16 + lr];
#pragma unroll
      for (int i = 0; i < 4; ++i) {
        int tq = sTq[wave * 16 + lq * 4 + i];
        float sv = sacc[cn][i] * scale + ((tq < tk) ? -1e9f : 0.f);
        sval[cn][i] = sv;
        mt[i] = fmaxf(mt[i], sv);
      }
    }
#pragma unroll
    for (int i = 0; i < 4; ++i) {
#pragma unroll
      for (int m = 1; m < 16; m <<= 1) mt[i] = fmaxf(mt[i], __shfl_xor(mt[i], m));
    }
    float fsc[4], lt[4];
    __bf16* sPw = sP[wave];
#pragma unroll
    for (int i = 0; i < 4; ++i) {
      float mnew = fmaxf(m_run[i], mt[i]);
      fsc[i] = __expf(m_run[i] - mnew);
      m_run[i] = mnew;
      lt[i] = 0.f;
    }
#pragma unroll
    for (int cn = 0; cn < 4; ++cn) {
#pragma unroll
      for (int i = 0; i < 4; ++i) {
        float p = __expf(sval[cn][i] - m_run[i]);
        lt[i] += p;
        int rp = lq * 4 + i;
        int kvx = cn * 16 + lr;
        sPw[(rp << 6) + ((((kvx >> 3) ^ rp) & 7) << 3) + (kvx & 7)] = (__bf16)p;
      }
    }
#pragma unroll
    for (int i = 0; i < 4; ++i) {
#pragma unroll
      for (int m = 1; m < 16; m <<= 1) lt[i] += __shfl_xor(lt[i], m);
      l_run[i] = l_run[i] * fsc[i] + lt[i];
    }
#pragma unroll
    for (int dn = 0; dn < 4; ++dn)
#pragma unroll
      for (int i = 0; i < 4; ++i) oacc[dn][i] *= fsc[i];

    // PV: O += P[16,64] * V[64,64]
#pragma unroll
    for (int kk = 0; kk < 2; ++kk) {
      bf16x8 ap = *(const bf16x8*)(sPw + swz(lr, kk * 4 + lq));
#pragma unroll
      for (int dn = 0; dn < 4; ++dn) {
        bf16x8 bv;
#pragma unroll
        for (int i2 = 0; i2 < 8; ++i2)
          bv[i2] = sV[(kk * 32 + lq * 8 + i2) * 64 + dn * 16 + lr];
        oacc[dn] = __builtin_amdgcn_mfma_f32_16x16x32_bf16(ap, bv, oacc[dn], 0, 0, 0);
      }
    }
  }
  // write O (normalize)
#pragma unroll
  for (int dn = 0; dn < 4; ++dn) {
#pragma unroll
    for (int i = 0; i < 4; ++i) {
      int rg = qt * 64 + wave * 16 + lq * 4 + i;
      if (rg < L_) {
        float val = oacc[dn][i] / l_run[i];
        o[((size_t)b * L_ + rg) * D_ + hh * DH + dn * 16 + lr] = (__bf16)val;
      }
    }
  }
}

// copy h[:, 8:, :] -> out (fp32)
__global__ void out_k(const float* __restrict__ h, float* __restrict__ out) {
  int idx = blockIdx.x * 256 + threadIdx.x;  // float4 units, 16*512*256
  int c4 = idx & 255;
  int r = (idx >> 8) & 511;
  int b = idx >> 17;
  ((float4*)out)[idx] = ((const float4*)h)[((size_t)b * L_ + NCTX + r) * 256 + c4];
}

// ---------- host ----------
extern "C" void kernel_launch(void* const* d_in, const int* in_sizes, int n_in,
                              void* d_out, int out_size, void* d_ws, size_t ws_size,
                              hipStream_t stream) {
  const float* latents      = (const float*)d_in[0];
  const int*   in_time_idx  = (const int*)d_in[1];
  const int*   query_idx    = (const int*)d_in[4];
  const int*   query_time   = (const int*)d_in[5];
  const float* ctx_emb      = (const float*)d_in[8];
  const float* query_emb_w  = (const float*)d_in[9];
  const float* time_emb_w   = (const float*)d_in[10];
  const float* qkv_w        = (const float*)d_in[11];
  const float* qkv_b        = (const float*)d_in[12];
  const float* out_w        = (const float*)d_in[13];
  const float* out_b        = (const float*)d_in[14];
  const float* ln1_s        = (const float*)d_in[15];
  const float* ln1_b        = (const float*)d_in[16];
  const float* ln2_s        = (const float*)d_in[17];
  const float* ln2_b        = (const float*)d_in[18];
  const float* w1           = (const float*)d_in[19];
  const float* b1           = (const float*)d_in[20];
  const float* w2           = (const float*)d_in[21];
  const float* b2           = (const float*)d_in[22];

  size_t off = 0;
  auto alloc = [&](size_t n) { char* p = (char*)d_ws + off; off += (n + 255) & ~(size_t)255; return (void*)p; };
  float*  h    = (float*)alloc((size_t)MP * D_ * 4);
  __bf16* y    = (__bf16*)alloc((size_t)MP * D_ * 2);        // ln out / attn out
  __bf16* qkvb = (__bf16*)alloc((size_t)MP * 3 * D_ * 2);
  __bf16* mid  = (__bf16*)alloc((size_t)MP * DFF_ * 2);
  __bf16* wq   = (__bf16*)alloc((size_t)3 * D_ * D_ * 2);
  __bf16* wo   = (__bf16*)alloc((size_t)D_ * D_ * 2);
  __bf16* w1b  = (__bf16*)alloc((size_t)DFF_ * D_ * 2);
  __bf16* w2b  = (__bf16*)alloc((size_t)D_ * DFF_ * 2);
  int*    Te   = (int*)alloc((size_t)B_ * 576 * 4);
  int*    TeMn = (int*)alloc((size_t)B_ * 9 * 4);
  int*    TeMx = (int*)alloc((size_t)B_ * 9 * 4);
  (void)ws_size; (void)in_sizes; (void)n_in; (void)out_size;

  te_k<<<B_, 576, 0, stream>>>(query_time, Te, TeMn, TeMx);
  pool_k<<<dim3(BIN_, B_), 256, 0, stream>>>(latents, in_time_idx, time_emb_w, h);
  qrows_k<<<dim3(NCTX + LQ_, B_), 256, 0, stream>>>(ctx_emb, query_emb_w, time_emb_w,
                                                    query_idx, query_time, h);
  const int GY = MP / 256;  // 33
  for (int l = 0; l < DEPTH; ++l) {
    cvt_k<<<2048, 256, 0, stream>>>(qkv_w + (size_t)l * 3 * D_ * D_, wq, 3 * D_ * D_ / 4);
    cvt_k<<<2048, 256, 0, stream>>>(out_w + (size_t)l * D_ * D_, wo, D_ * D_ / 4);
    cvt_k<<<2048, 256, 0, stream>>>(w1 + (size_t)l * DFF_ * D_, w1b, DFF_ * D_ / 4);
    cvt_k<<<2048, 256, 0, stream>>>(w2 + (size_t)l * D_ * DFF_, w2b, D_ * DFF_ / 4);

    ln_k<<<MROWS, 256, 0, stream>>>(h, ln1_s + l * D_, ln1_b + l * D_, y);
    gemm256_k<0><<<(3 * D_ / 256) * GY, 512, 0, stream>>>(
        y, wq, qkv_b + (size_t)l * 3 * D_, qkvb, nullptr, 3 * D_, D_, 3 * D_ / 256);
    attn_k<<<dim3(9, H_, B_), 256, 0, stream>>>(qkvb, Te, TeMn, TeMx, y);
    gemm256_k<1><<<(D_ / 256) * GY, 512, 0, stream>>>(
        y, wo, out_b + (size_t)l * D_, nullptr, h, D_, D_, D_ / 256);
    ln_k<<<MROWS, 256, 0, stream>>>(h, ln2_s + l * D_, ln2_b + l * D_, y);
    gemm256_k<2><<<(DFF_ / 256) * GY, 512, 0, stream>>>(
        y, w1b, b1 + (size_t)l * DFF_, mid, nullptr, DFF_, D_, DFF_ / 256);
    gemm256_k<1><<<(D_ / 256) * GY, 512, 0, stream>>>(
        mid, w2b, b2 + (size_t)l * D_, nullptr, h, D_, DFF_, D_ / 256);
  }
  out_k<<<(B_ * 512 * 256) / 256, 256, 0, stream>>>(h, (float*)d_out);
}

// Round 3
// 3014.264 us; speedup vs baseline: 1.1741x; 1.1741x over previous
//
#include <hip/hip_runtime.h>

// ---------- constants ----------
#define B_    16
#define NCTX  8
#define BIN_  256
#define LQ_   256
#define L_    520          // NCTX + BIN + LQ
#define LSEQ  1024
#define D_    1024
#define H_    16
#define DH    64
#define DFF_  4096
#define DEPTH 6
#define MROWS (B_ * L_)    // 8320 = 65 * 128
#define GY    65           // M tiles of 128

using bf16x8 = __attribute__((ext_vector_type(8))) __bf16;
using bf16x4 = __attribute__((ext_vector_type(4))) __bf16;
using f32x4  = __attribute__((ext_vector_type(4))) float;

#define DEV __device__ __forceinline__

// element offset into a [rows][64] bf16 tile, XOR-swizzled 16B chunks
DEV int swz(int r, int c) { return (r << 6) + (((c ^ r) & 7) << 3); }

#define GLDS16(g, l)                                                         \
  __builtin_amdgcn_global_load_lds(                                          \
      (__attribute__((address_space(1))) void*)(g),                          \
      (__attribute__((address_space(3))) void*)(l), 16, 0, 0)

// ---------- prologue kernels ----------

// Te[b][pos]: time key per decoder position, plus per-64-tile K-min and
// Q-max (over real rows) for attention tile skipping.
__global__ void te_k(const int* __restrict__ qtime, int* __restrict__ Te,
                     int* __restrict__ TeMinK, int* __restrict__ TeMaxQ) {
  int b = blockIdx.x, pos = threadIdx.x;
  __shared__ int smin[9], smax[9];
  if (pos < 9) { smin[pos] = 0x7fffffff; smax[pos] = (int)0x80000000; }
  __syncthreads();
  int v;
  if (pos < NCTX) v = (int)0x80000000;
  else if (pos < NCTX + BIN_) v = pos - NCTX;
  else if (pos < L_) v = qtime[b * LQ_ + (pos - NCTX - BIN_)];
  else v = 0x7fffffff;
  Te[b * 576 + pos] = v;
  int vq = (pos < L_) ? v : (int)0x80000000;
  atomicMin(&smin[pos >> 6], v);
  atomicMax(&smax[pos >> 6], vq);
  __syncthreads();
  if (pos < 9) { TeMinK[b * 9 + pos] = smin[pos]; TeMaxQ[b * 9 + pos] = smax[pos]; }
}

// mean-pool latents per time bin, add time embedding, write h rows 8..263
__global__ void pool_k(const float* __restrict__ latents,
                       const int* __restrict__ tIdx,
                       const float* __restrict__ temb, float* __restrict__ h) {
  int s = blockIdx.x, b = blockIdx.y, tid = threadIdx.x;
  __shared__ int sIdx[LSEQ];
#pragma unroll
  for (int j = 0; j < 4; ++j) sIdx[tid + 256 * j] = tIdx[b * LSEQ + tid + 256 * j];
  __syncthreads();
  float a0 = 0.f, a1 = 0.f, a2 = 0.f, a3 = 0.f;
  int cnt = 0;
  const float4* L = (const float4*)(latents + (size_t)b * LSEQ * D_);
  for (int l = 0; l < LSEQ; ++l) {
    if (sIdx[l] == s) {
      float4 v = L[(size_t)l * 256 + tid];
      a0 += v.x; a1 += v.y; a2 += v.z; a3 += v.w; ++cnt;
    }
  }
  float inv = 1.f / (float)(cnt > 0 ? cnt : 1);
  float4 te = ((const float4*)(temb + (size_t)s * D_))[tid];
  float4 o;
  o.x = a0 * inv + te.x; o.y = a1 * inv + te.y;
  o.z = a2 * inv + te.z; o.w = a3 * inv + te.w;
  ((float4*)(h + ((size_t)b * L_ + NCTX + s) * D_))[tid] = o;
}

// ctx rows (0..7) + query rows (264..519)
__global__ void qrows_k(const float* __restrict__ ctx,
                        const float* __restrict__ qemb,
                        const float* __restrict__ temb,
                        const int* __restrict__ qidx,
                        const int* __restrict__ qtime, float* __restrict__ h) {
  int r = blockIdx.x, b = blockIdx.y, tid = threadIdx.x;
  if (r < NCTX) {
    float4 v = ((const float4*)(ctx + ((size_t)b * NCTX + r) * D_))[tid];
    ((float4*)(h + ((size_t)b * L_ + r) * D_))[tid] = v;
  } else {
    int q = r - NCTX;
    int qi = qidx[b * LQ_ + q];
    int qt = qtime[b * LQ_ + q];
    float4 e = ((const float4*)(qemb + (size_t)qi * D_))[tid];
    float4 t = ((const float4*)(temb + (size_t)qt * D_))[tid];
    float4 o; o.x = e.x + t.x; o.y = e.y + t.y; o.z = e.z + t.z; o.w = e.w + t.w;
    ((float4*)(h + ((size_t)b * L_ + NCTX + BIN_ + q) * D_))[tid] = o;
  }
}

// one launch per layer: convert all 4 weight slabs fp32 -> bf16
// slab sizes (float4 units): 786432 / 262144 / 1048576 / 1048576
__global__ void cvt4_k(const float* __restrict__ s0, const float* __restrict__ s1,
                       const float* __restrict__ s2, const float* __restrict__ s3,
                       __bf16* __restrict__ dst) {
  int i = blockIdx.x * 256 + threadIdx.x;  // 3145728 total
  const float* s; int off;
  if (i < 786432)       { s = s0; off = i; }
  else if (i < 1048576) { s = s1; off = i - 786432; }
  else if (i < 2097152) { s = s2; off = i - 1048576; }
  else                  { s = s3; off = i - 2097152; }
  float4 v = ((const float4*)s)[off];
  bf16x4 o;
  o[0] = (__bf16)v.x; o[1] = (__bf16)v.y; o[2] = (__bf16)v.z; o[3] = (__bf16)v.w;
  ((bf16x4*)dst)[i] = o;
}

// LayerNorm over D=1024, fp32 in -> bf16 out
__global__ __launch_bounds__(256) void ln_k(const float* __restrict__ h,
                                            const float* __restrict__ s,
                                            const float* __restrict__ bb,
                                            __bf16* __restrict__ y) {
  int row = blockIdx.x, tid = threadIdx.x;
  int lane = tid & 63, wave = tid >> 6;
  float4 v = ((const float4*)(h + (size_t)row * D_))[tid];
  float sum = v.x + v.y + v.z + v.w;
  float sq  = v.x * v.x + v.y * v.y + v.z * v.z + v.w * v.w;
#pragma unroll
  for (int m = 32; m; m >>= 1) { sum += __shfl_xor(sum, m); sq += __shfl_xor(sq, m); }
  __shared__ float red[8];
  if (lane == 0) { red[wave] = sum; red[4 + wave] = sq; }
  __syncthreads();
  sum = red[0] + red[1] + red[2] + red[3];
  sq  = red[4] + red[5] + red[6] + red[7];
  float mean = sum * (1.f / D_);
  float var  = sq * (1.f / D_) - mean * mean;
  float rstd = rsqrtf(var + 1e-5f);
  float4 sv = ((const float4*)s)[tid];
  float4 bv = ((const float4*)bb)[tid];
  bf16x4 o;
  o[0] = (__bf16)((v.x - mean) * rstd * sv.x + bv.x);
  o[1] = (__bf16)((v.y - mean) * rstd * sv.y + bv.y);
  o[2] = (__bf16)((v.z - mean) * rstd * sv.z + bv.z);
  o[3] = (__bf16)((v.w - mean) * rstd * sv.w + bv.w);
  *(bf16x4*)(y + (size_t)row * D_ + tid * 4) = o;
}

// ---------- GEMM: C[M,N] = A[M,K] * Bw[N,K]^T + bias (128x128 tile) ----------
// 1D grid gx*65, XCD-bijective chunk + 8-row supertile bands for L2 locality.
// EPI 0: store bf16; 1: outF += val (fp32 residual); 2: gelu -> bf16
template <int EPI>
__global__ __launch_bounds__(256) void gemm_k(const __bf16* __restrict__ A,
                                              const __bf16* __restrict__ Bw,
                                              const float* __restrict__ bias,
                                              __bf16* __restrict__ outB,
                                              float* __restrict__ outF,
                                              int N, int K, int gx) {
  __shared__ __bf16 sA[128 * 64];
  __shared__ __bf16 sB[128 * 64];
  const int tid = threadIdx.x;
  const int lane = tid & 63, wave = tid >> 6;
  const int lr = lane & 15, lq = lane >> 4;
  const int wr = wave >> 1, wc = wave & 1;

  // XCD-bijective remap (nwg always % 8 == 0 here) then 8-row supertile bands
  const int nwg = gridDim.x;
  int hid = blockIdx.x;
  int lid = (hid & 7) * (nwg >> 3) + (hid >> 3);
  int per_band = gx << 3;
  int band = lid / per_band;
  int rem = lid - band * per_band;
  int rows = min(8, GY - (band << 3));
  int by = (band << 3) + rem % rows;
  int bx = rem / rows;
  const size_t bm = (size_t)by * 128;
  const size_t bn = (size_t)bx * 128;

  f32x4 acc[4][4] = {};

  int stage_r[4], stage_src[4];
#pragma unroll
  for (int j = 0; j < 4; ++j) {
    int q = (wave * 4 + j) * 64 + lane;
    int r = q >> 3, c = q & 7;
    stage_r[j] = r;
    stage_src[j] = ((c ^ r) & 7) << 3;  // pre-swizzled global chunk
  }
  const __bf16* Ab = A + bm * (size_t)K;
  const __bf16* Bb = Bw + bn * (size_t)K;
  const int nk = K >> 6;
  for (int kt = 0; kt < nk; ++kt) {
    const __bf16* Ak = Ab + kt * 64;
    const __bf16* Bk = Bb + kt * 64;
#pragma unroll
    for (int j = 0; j < 4; ++j) {
      int r = stage_r[j];
      GLDS16(Ak + (size_t)r * K + stage_src[j], sA + (wave * 4 + j) * 512);
      GLDS16(Bk + (size_t)r * K + stage_src[j], sB + (wave * 4 + j) * 512);
    }
    __syncthreads();
#pragma unroll
    for (int kk = 0; kk < 2; ++kk) {
      bf16x8 af[4], bfm[4];
#pragma unroll
      for (int im = 0; im < 4; ++im)
        af[im] = *(const bf16x8*)(sA + swz(wr * 64 + im * 16 + lr, kk * 4 + lq));
#pragma unroll
      for (int in = 0; in < 4; ++in)
        bfm[in] = *(const bf16x8*)(sB + swz(wc * 64 + in * 16 + lr, kk * 4 + lq));
#pragma unroll
      for (int im = 0; im < 4; ++im)
#pragma unroll
        for (int in = 0; in < 4; ++in)
          acc[im][in] = __builtin_amdgcn_mfma_f32_16x16x32_bf16(af[im], bfm[in], acc[im][in], 0, 0, 0);
    }
    __syncthreads();
  }
  const int r0 = (int)bm + wr * 64 + lq * 4;
  const int c0 = (int)bn + wc * 64 + lr;
#pragma unroll
  for (int in = 0; in < 4; ++in) {
    int cg = c0 + in * 16;
    float bl = bias[cg];
#pragma unroll
    for (int im = 0; im < 4; ++im) {
      f32x4 v = acc[im][in];
#pragma unroll
      for (int i = 0; i < 4; ++i) {
        int rg = r0 + im * 16 + i;
        float val = v[i] + bl;
        if (EPI == 0) {
          outB[(size_t)rg * N + cg] = (__bf16)val;
        } else if (EPI == 1) {
          outF[(size_t)rg * N + cg] += val;
        } else {
          float g = 0.5f * val * (1.0f + erff(val * 0.70710678118f));
          outB[(size_t)rg * N + cg] = (__bf16)g;
        }
      }
    }
  }
}

// ---------- attention ----------
// grid (qt=9, h=16, b=16), 256 threads (4 waves); each wave owns 16 q rows.
// Fully-masked (qt,kt) tile pairs are skipped (time keys sorted).
__global__ __launch_bounds__(256) void attn_k(const __bf16* __restrict__ qkv,
                                              const int* __restrict__ Te,
                                              const int* __restrict__ TeMinK,
                                              const int* __restrict__ TeMaxQ,
                                              __bf16* __restrict__ o) {
  const int qt = blockIdx.x, hh = blockIdx.y, b = blockIdx.z;
  const int tid = threadIdx.x;
  const int lane = tid & 63, wave = tid >> 6;
  const int lr = lane & 15, lq = lane >> 4;
  __shared__ __bf16 sQ[64 * 64], sK[64 * 64], sV[64 * 64];
  __shared__ __bf16 sP[4][16 * 64];
  __shared__ int sTq[64], sTk[64];

  if (tid < 64) sTq[tid] = Te[b * 576 + qt * 64 + tid];
  const int maxQ = TeMaxQ[b * 9 + qt];

  const __bf16* base = qkv + (size_t)b * L_ * (3 * D_) + hh * DH;
  // stage Q (swizzled write, zero-fill invalid rows)
#pragma unroll
  for (int j = 0; j < 2; ++j) {
    int q = tid + j * 256;
    int r = q >> 3, c = q & 7;
    int rg = qt * 64 + r;
    bf16x8 v = {};
    if (rg < L_) v = *(const bf16x8*)(base + (size_t)rg * (3 * D_) + c * 8);
    *(bf16x8*)(sQ + swz(r, c)) = v;
  }

  float m_run[4], l_run[4];
#pragma unroll
  for (int i = 0; i < 4; ++i) { m_run[i] = -1e30f; l_run[i] = 0.f; }
  f32x4 oacc[4] = {};
  const float scale = 0.125f;

  for (int kt = 0; kt < 9; ++kt) {
    if (TeMinK[b * 9 + kt] > maxQ) continue;  // tile fully masked (uniform)
    __syncthreads();  // previous tile fully consumed
    if (tid < 64) sTk[tid] = Te[b * 576 + kt * 64 + tid];
#pragma unroll
    for (int j = 0; j < 2; ++j) {
      int q = tid + j * 256;
      int r = q >> 3, c = q & 7;
      int rg = kt * 64 + r;
      bf16x8 kv = {}, vv = {};
      if (rg < L_) {
        kv = *(const bf16x8*)(base + D_ + (size_t)rg * (3 * D_) + c * 8);
        vv = *(const bf16x8*)(base + 2 * D_ + (size_t)rg * (3 * D_) + c * 8);
      }
      *(bf16x8*)(sK + swz(r, c)) = kv;       // swizzled
      *(bf16x8*)(sV + r * 64 + c * 8) = vv;  // linear
    }
    __syncthreads();

    // S = Q K^T (wave strip: rows wave*16..+16, cols 0..64)
    f32x4 sacc[4] = {};
#pragma unroll
    for (int kk = 0; kk < 2; ++kk) {
      bf16x8 aq = *(const bf16x8*)(sQ + swz(wave * 16 + lr, kk * 4 + lq));
#pragma unroll
      for (int cn = 0; cn < 4; ++cn) {
        bf16x8 bk = *(const bf16x8*)(sK + swz(cn * 16 + lr, kk * 4 + lq));
        sacc[cn] = __builtin_amdgcn_mfma_f32_16x16x32_bf16(aq, bk, sacc[cn], 0, 0, 0);
      }
    }
    // mask + online softmax (rows: lq*4+i, cols: cn*16+lr)
    float sval[4][4], mt[4];
#pragma unroll
    for (int i = 0; i < 4; ++i) mt[i] = -1e30f;
#pragma unroll
    for (int cn = 0; cn < 4; ++cn) {
      int tk = sTk[cn * 16 + lr];
#pragma unroll
      for (int i = 0; i < 4; ++i) {
        int tq = sTq[wave * 16 + lq * 4 + i];
        float sv = sacc[cn][i] * scale + ((tq < tk) ? -1e9f : 0.f);
        sval[cn][i] = sv;
        mt[i] = fmaxf(mt[i], sv);
      }
    }
#pragma unroll
    for (int i = 0; i < 4; ++i) {
#pragma unroll
      for (int m = 1; m < 16; m <<= 1) mt[i] = fmaxf(mt[i], __shfl_xor(mt[i], m));
    }
    float fsc[4], lt[4];
    __bf16* sPw = sP[wave];
#pragma unroll
    for (int i = 0; i < 4; ++i) {
      float mnew = fmaxf(m_run[i], mt[i]);
      fsc[i] = __expf(m_run[i] - mnew);
      m_run[i] = mnew;
      lt[i] = 0.f;
    }
#pragma unroll
    for (int cn = 0; cn < 4; ++cn) {
#pragma unroll
      for (int i = 0; i < 4; ++i) {
        float p = __expf(sval[cn][i] - m_run[i]);
        lt[i] += p;
        int rp = lq * 4 + i;
        int kvx = cn * 16 + lr;
        sPw[(rp << 6) + ((((kvx >> 3) ^ rp) & 7) << 3) + (kvx & 7)] = (__bf16)p;
      }
    }
#pragma unroll
    for (int i = 0; i < 4; ++i) {
#pragma unroll
      for (int m = 1; m < 16; m <<= 1) lt[i] += __shfl_xor(lt[i], m);
      l_run[i] = l_run[i] * fsc[i] + lt[i];
    }
#pragma unroll
    for (int dn = 0; dn < 4; ++dn)
#pragma unroll
      for (int i = 0; i < 4; ++i) oacc[dn][i] *= fsc[i];

    // PV: O += P[16,64] * V[64,64]
#pragma unroll
    for (int kk = 0; kk < 2; ++kk) {
      bf16x8 ap = *(const bf16x8*)(sPw + swz(lr, kk * 4 + lq));
#pragma unroll
      for (int dn = 0; dn < 4; ++dn) {
        bf16x8 bv;
#pragma unroll
        for (int i2 = 0; i2 < 8; ++i2)
          bv[i2] = sV[(kk * 32 + lq * 8 + i2) * 64 + dn * 16 + lr];
        oacc[dn] = __builtin_amdgcn_mfma_f32_16x16x32_bf16(ap, bv, oacc[dn], 0, 0, 0);
      }
    }
  }
  // write O (normalize)
#pragma unroll
  for (int dn = 0; dn < 4; ++dn) {
#pragma unroll
    for (int i = 0; i < 4; ++i) {
      int rg = qt * 64 + wave * 16 + lq * 4 + i;
      if (rg < L_) {
        float val = oacc[dn][i] / l_run[i];
        o[((size_t)b * L_ + rg) * D_ + hh * DH + dn * 16 + lr] = (__bf16)val;
      }
    }
  }
}

// copy h[:, 8:, :] -> out (fp32)
__global__ void out_k(const float* __restrict__ h, float* __restrict__ out) {
  int idx = blockIdx.x * 256 + threadIdx.x;  // float4 units, 16*512*256
  int c4 = idx & 255;
  int r = (idx >> 8) & 511;
  int b = idx >> 17;
  ((float4*)out)[idx] = ((const float4*)h)[((size_t)b * L_ + NCTX + r) * 256 + c4];
}

// ---------- host ----------
extern "C" void kernel_launch(void* const* d_in, const int* in_sizes, int n_in,
                              void* d_out, int out_size, void* d_ws, size_t ws_size,
                              hipStream_t stream) {
  const float* latents      = (const float*)d_in[0];
  const int*   in_time_idx  = (const int*)d_in[1];
  const int*   query_idx    = (const int*)d_in[4];
  const int*   query_time   = (const int*)d_in[5];
  const float* ctx_emb      = (const float*)d_in[8];
  const float* query_emb_w  = (const float*)d_in[9];
  const float* time_emb_w   = (const float*)d_in[10];
  const float* qkv_w        = (const float*)d_in[11];
  const float* qkv_b        = (const float*)d_in[12];
  const float* out_w        = (const float*)d_in[13];
  const float* out_b        = (const float*)d_in[14];
  const float* ln1_s        = (const float*)d_in[15];
  const float* ln1_b        = (const float*)d_in[16];
  const float* ln2_s        = (const float*)d_in[17];
  const float* ln2_b        = (const float*)d_in[18];
  const float* w1           = (const float*)d_in[19];
  const float* b1           = (const float*)d_in[20];
  const float* w2           = (const float*)d_in[21];
  const float* b2           = (const float*)d_in[22];

  size_t off = 0;
  auto alloc = [&](size_t n) { char* p = (char*)d_ws + off; off += (n + 255) & ~(size_t)255; return (void*)p; };
  float*  h    = (float*)alloc((size_t)MROWS * D_ * 4);
  __bf16* y    = (__bf16*)alloc((size_t)MROWS * D_ * 2);        // ln out / attn out
  __bf16* qkvb = (__bf16*)alloc((size_t)MROWS * 3 * D_ * 2);
  __bf16* mid  = (__bf16*)alloc((size_t)MROWS * DFF_ * 2);
  __bf16* wsl  = (__bf16*)alloc((size_t)12582912 * 2);          // wq|wo|w1|w2 bf16
  int*    Te   = (int*)alloc((size_t)B_ * 576 * 4);
  int*    TeMn = (int*)alloc((size_t)B_ * 9 * 4);
  int*    TeMx = (int*)alloc((size_t)B_ * 9 * 4);
  (void)ws_size; (void)in_sizes; (void)n_in; (void)out_size;
  __bf16* wq  = wsl;
  __bf16* wo  = wsl + 3145728;
  __bf16* w1b = wsl + 4194304;
  __bf16* w2b = wsl + 8388608;

  te_k<<<B_, 576, 0, stream>>>(query_time, Te, TeMn, TeMx);
  pool_k<<<dim3(BIN_, B_), 256, 0, stream>>>(latents, in_time_idx, time_emb_w, h);
  qrows_k<<<dim3(NCTX + LQ_, B_), 256, 0, stream>>>(ctx_emb, query_emb_w, time_emb_w,
                                                    query_idx, query_time, h);
  for (int l = 0; l < DEPTH; ++l) {
    cvt4_k<<<12288, 256, 0, stream>>>(qkv_w + (size_t)l * 3145728, out_w + (size_t)l * 1048576,
                                      w1 + (size_t)l * 4194304, w2 + (size_t)l * 4194304, wsl);

    ln_k<<<MROWS, 256, 0, stream>>>(h, ln1_s + l * D_, ln1_b + l * D_, y);
    gemm_k<0><<<24 * GY, 256, 0, stream>>>(
        y, wq, qkv_b + (size_t)l * 3 * D_, qkvb, nullptr, 3 * D_, D_, 24);
    attn_k<<<dim3(9, H_, B_), 256, 0, stream>>>(qkvb, Te, TeMn, TeMx, y);
    gemm_k<1><<<8 * GY, 256, 0, stream>>>(
        y, wo, out_b + (size_t)l * D_, nullptr, h, D_, D_, 8);
    ln_k<<<MROWS, 256, 0, stream>>>(h, ln2_s + l * D_, ln2_b + l * D_, y);
    gemm_k<2><<<32 * GY, 256, 0, stream>>>(
        y, w1b, b1 + (size_t)l * DFF_, mid, nullptr, DFF_, D_, 32);
    gemm_k<1><<<8 * GY, 256, 0, stream>>>(
        mid, w2b, b2 + (size_t)l * D_, nullptr, h, D_, DFF_, 8);
  }
  out_k<<<(B_ * 512 * 256) / 256, 256, 0, stream>>>(h, (float*)d_out);
}